// Round 9
// baseline (198.253 us; speedup 1.0000x reference)
//
#include <hip/hip_runtime.h>
#include <cstdint>
#include <cstddef>

// ---- problem constants ----
#define D_MODEL 1024
#define S_LEN   2048
#define NHEAD   16
#define DHEAD   64
#define BSZ     2
#define LOG2E   1.44269504088896f

typedef short  short8   __attribute__((ext_vector_type(8)));
typedef float  floatx4  __attribute__((ext_vector_type(4)));
typedef float  floatx16 __attribute__((ext_vector_type(16)));
typedef unsigned short u16x4 __attribute__((ext_vector_type(4)));

#define VM4  __asm__ volatile("s_waitcnt vmcnt(4)" ::: "memory")
#define VM3  __asm__ volatile("s_waitcnt vmcnt(3)" ::: "memory")
#define VM0  __asm__ volatile("s_waitcnt vmcnt(0)" ::: "memory")
#define LG0  __asm__ volatile("s_waitcnt lgkmcnt(0)" ::: "memory")
#define SBAR __builtin_amdgcn_s_barrier()
#define SCHED __builtin_amdgcn_sched_barrier(0)

__device__ inline unsigned short f2b(float f) {
  union { float f; unsigned int u; } v; v.f = f;
  unsigned int r = v.u + 0x7FFFu + ((v.u >> 16) & 1u);   // RNE
  return (unsigned short)(r >> 16);
}

// async global->LDS, 16B per lane. LDS dest must be wave-uniform base (+lane*16 implicit).
__device__ inline void gload_lds16(const void* g, void* l) {
  __builtin_amdgcn_global_load_lds(
      (const __attribute__((address_space(1))) unsigned int*)g,
      (__attribute__((address_space(3))) unsigned int*)l, 16, 0, 0);
}

// ---------------- kernel 1: fused prep (x->bf16 convert + 4 weight transpose-converts) ----------------
__global__ __launch_bounds__(256) void k_prep(
    const float* __restrict__ x,
    const float* __restrict__ wq, const float* __restrict__ wk,
    const float* __restrict__ wv, const float* __restrict__ wo,
    unsigned short* __restrict__ xb, unsigned short* __restrict__ wqkvT,
    unsigned short* __restrict__ woT) {
  int bid = blockIdx.x;
  if (bid < 4096) {
    int i = bid * 256 + threadIdx.x;
    float4 f = ((const float4*)x)[i];
    u16x4 o;
    o[0] = f2b(f.x); o[1] = f2b(f.y); o[2] = f2b(f.z); o[3] = f2b(f.w);
    ((u16x4*)xb)[i] = o;
    return;
  }
  __shared__ float tile[32][33];
  int r = bid - 4096;
  int which = r >> 10, tl = r & 1023;
  const float* src = (which == 0) ? wq : (which == 1) ? wk : (which == 2) ? wv : wo;
  unsigned short* dst = (which < 3) ? (wqkvT + (size_t)which * 1024 * 1024) : woT;
  int bx = (tl & 31) * 32;   // n block
  int by = (tl >> 5) * 32;   // k block
  int tx = threadIdx.x & 31, ty0 = threadIdx.x >> 5;
  #pragma unroll
  for (int i = 0; i < 4; i++) {
    int ty = ty0 + i * 8;
    tile[ty][tx] = src[(size_t)(by + ty) * D_MODEL + bx + tx];
  }
  __syncthreads();
  #pragma unroll
  for (int i = 0; i < 4; i++) {
    int ty = ty0 + i * 8;
    dst[(size_t)(bx + ty) * D_MODEL + by + tx] = f2b(tile[tx][ty]);
  }
}

// ---------------- shared GEMM mainloop: 128x128 tile, BK=32, TRIPLE-buffered, counted vmcnt ----------------
__device__ inline void gemm_tiles(const unsigned short* __restrict__ A,
                                  const unsigned short* __restrict__ Bt,
                                  int m0, int n0, char* lds, floatx4 acc[4][4]) {
  const int t = threadIdx.x, w = t >> 6, lane = t & 63;
  const int wr = w >> 1, wc = w & 1, g = lane >> 4, l15 = lane & 15;
  floatx4 zf = {0.f, 0.f, 0.f, 0.f};
  #pragma unroll
  for (int m = 0; m < 4; m++)
    #pragma unroll
    for (int n = 0; n < 4; n++) acc[m][n] = zf;

  auto stage = [&](int kt, int bi) {
    #pragma unroll
    for (int i = 0; i < 2; i++) {
      int p = i * 256 + t;
      int row = p >> 2, ce = (p & 3) << 3;
      gload_lds16(A  + (size_t)(m0 + row) * D_MODEL + kt * 32 + ce,
                  lds + bi * 8192 + i * 4096 + w * 1024);
      gload_lds16(Bt + (size_t)(n0 + row) * D_MODEL + kt * 32 + ce,
                  lds + 24576 + bi * 8192 + i * 4096 + w * 1024);
    }
  };

  stage(0, 0);
  stage(1, 1);
  int bi = 0;
  for (int kt = 0; kt < 32; kt++) {
    if (kt < 31) { VM4; } else { VM0; }
    SBAR; SCHED;
    if (kt < 30) {
      int b2 = bi + 2; if (b2 >= 3) b2 -= 3;
      stage(kt + 2, b2);
    }
    const char* As = lds + bi * 8192;
    const char* Bs = lds + 24576 + bi * 8192;
    short8 af[4], bfr[4];
    #pragma unroll
    for (int m = 0; m < 4; m++)
      af[m] = *(const short8*)(As + (wr * 64 + m * 16 + l15) * 64 + g * 16);
    #pragma unroll
    for (int n = 0; n < 4; n++)
      bfr[n] = *(const short8*)(Bs + (wc * 64 + n * 16 + l15) * 64 + g * 16);
    __builtin_amdgcn_s_setprio(1);
    #pragma unroll
    for (int m = 0; m < 4; m++)
      #pragma unroll
      for (int n = 0; n < 4; n++)
        acc[m][n] = __builtin_amdgcn_mfma_f32_16x16x32_bf16(af[m], bfr[n], acc[m][n], 0, 0, 0);
    __builtin_amdgcn_s_setprio(0);
    bi++; if (bi == 3) bi = 0;
  }
}

// ---------------- kernel 2: QKV GEMM, epilogue scatters Q/K per-head and V TRANSPOSED ----------------
__global__ __launch_bounds__(256, 3) void k_gemm_qkv(
    const unsigned short* __restrict__ xb, const unsigned short* __restrict__ wT,
    const float* __restrict__ bq, const float* __restrict__ bk, const float* __restrict__ bv,
    unsigned short* __restrict__ qb, unsigned short* __restrict__ kb,
    unsigned short* __restrict__ vtb) {
  __shared__ __align__(16) char lds[49152];
  floatx4 acc[4][4];
  int m0 = blockIdx.y * 128, n0 = blockIdx.x * 128;
  gemm_tiles(xb, wT, m0, n0, lds, acc);
  int t = threadIdx.x, w = t >> 6, lane = t & 63;
  int wr = w >> 1, wc = w & 1, g = lane >> 4, l15 = lane & 15;
  #pragma unroll
  for (int m = 0; m < 4; m++) {
    #pragma unroll
    for (int n = 0; n < 4; n++) {
      int row0 = m0 + wr * 64 + m * 16 + g * 4;          // token base (4 j's contiguous)
      int col  = n0 + wc * 64 + n * 16 + l15;            // 0..3071
      int sel = col >> 10, c = col & 1023;
      int h = c >> 6, dd = c & 63;
      int b_ = row0 >> 11, ss = row0 & 2047;
      if (sel == 2) {
        u16x4 o;
        #pragma unroll
        for (int j = 0; j < 4; j++) o[j] = f2b(acc[m][n][j] + bv[c]);
        *(u16x4*)(vtb + ((size_t)(b_ * NHEAD + h) * DHEAD + dd) * S_LEN + ss) = o;
      } else {
        const float* bias = (sel == 0) ? bq : bk;
        unsigned short* dst = (sel == 0) ? qb : kb;
        float sc = (sel == 0) ? 0.125f * LOG2E : 1.0f;
        #pragma unroll
        for (int j = 0; j < 4; j++) {
          float v = (acc[m][n][j] + bias[c]) * sc;
          dst[(size_t)((b_ * NHEAD + h) * S_LEN + ss + j) * DHEAD + dd] = f2b(v);
        }
      }
    }
  }
}

// ---------------- kernel 3: flash attention, 4 waves = (qh, kvh) quadrants ----------------
// Round-8 structure (verified correct) with the register budget fixed: waves_per_eu pinned
// to (4,4) -> VGPR cap 128 (round 8's launch_bounds form squeezed to 64 and spilled:
// WRITE_SIZE 8.2->13.3MB). Softmax transients shrunk: exp2 in-place on S, per-ks
// pack->permlane->PV so only 4 pack regs live at once.
__global__ __launch_bounds__(256)
__attribute__((amdgpu_waves_per_eu(4, 4)))
void k_attn(
    const unsigned short* __restrict__ Q, const unsigned short* __restrict__ K,
    const unsigned short* __restrict__ Vt, unsigned short* __restrict__ O) {
  __shared__ __align__(16) char lds[33280];
  char* KsB0 = lds;              // 8KB K buf0
  char* KsB1 = lds + 8192;
  char* VsB0 = lds + 16384;      // 8KB V buf0
  char* VsB1 = lds + 24576;      // 8KB V buf1 (holds Q during prologue)
  float* Lx  = (float*)(lds + 32768);   // 128 floats: per-wave l exchange

  // XCD swizzle: bh -> XCD (bh&7); per-XCD KV working set = 4 bh * 512KB = 2MB (fits L2)
  int L = blockIdx.x;
  int bh = (L & 7) + 8 * (L >> 8);
  int qt = (L >> 3) & 31;

  int t = threadIdx.x, w = t >> 6, lane = t & 63, l31 = lane & 31, hi = lane >> 5;
  int qh = w & 1, kvh = w >> 1;
  const unsigned short* Qh = Q + (size_t)bh * S_LEN * DHEAD;
  const unsigned short* Kh = K + (size_t)bh * S_LEN * DHEAD;
  const unsigned short* Vh = Vt + (size_t)bh * DHEAD * S_LEN;
  int q0 = qt * 64;

  auto stageKV = [&](int kt, int b) {
    char* Kd = b ? KsB1 : KsB0;
    char* Vd = b ? VsB1 : VsB0;
    #pragma unroll
    for (int i = 0; i < 2; i++) {
      int p = i * 256 + t;
      int row = p >> 3;
      int sb = ((p & 7) ^ ((row ^ (row >> 3)) & 7)) << 4;
      gload_lds16(Kh + (size_t)(kt * 64 + row) * DHEAD + (sb >> 1), Kd + i * 4096 + w * 1024);
      gload_lds16(Vh + (size_t)row * S_LEN + kt * 64 + (sb >> 1),   Vd + i * 4096 + w * 1024);
    }
  };

  // prologue: stage Q (into VsB1) + KV tile 0 (buf0); one-time full drain
  #pragma unroll
  for (int i = 0; i < 2; i++) {
    int p = i * 256 + t;
    int row = p >> 3;
    int sb = ((p & 7) ^ ((row ^ (row >> 3)) & 7)) << 4;
    gload_lds16(Qh + (size_t)(q0 + row) * DHEAD + (sb >> 1), VsB1 + i * 4096 + w * 1024);
  }
  stageKV(0, 0);
  __syncthreads();                       // Q + tile0 landed (full drain, once)

  const int fr0 = ((l31 ^ (l31 >> 3)) & 7) << 4;
  short8 qf[4];
  #pragma unroll
  for (int ds = 0; ds < 4; ds++)
    qf[ds] = *(const short8*)(VsB1 + (qh * 32 + l31) * 128 + ((32 * ds + 16 * hi) ^ fr0 ^ (qh << 6)));
  LG0;                                   // Q in regs
  SBAR; SCHED;                           // all waves done reading VsB1
  stageKV(1, 1);                         // 4 loads in flight

  floatx16 accd[2];
  #pragma unroll
  for (int dt = 0; dt < 2; dt++)
    #pragma unroll
    for (int r = 0; r < 16; r++) accd[dt][r] = 0.f;
  float lsA = 0.f, lsB = 0.f;

  #pragma unroll 2
  for (int kt = 0; kt < S_LEN / 64; kt++) {
    int b = kt & 1;
    char* Ks = b ? KsB1 : KsB0;
    char* Vs = b ? VsB1 : VsB0;
    if (kt < S_LEN / 64 - 1) { VM4; } else { VM0; }   // tile kt landed; kt+1 in flight
    SBAR; SCHED;                                       // tile kt visible to all waves

    // S^T[kv32][q32] = K * Q^T for own quadrant: A rows kv = kvh*32 + l31
    short8 kf[4];
    #pragma unroll
    for (int ds = 0; ds < 4; ds++)
      kf[ds] = *(const short8*)(Ks + (kvh * 32 + l31) * 128 + ((32 * ds + 16 * hi) ^ fr0 ^ (kvh << 6)));
    floatx16 s;
    #pragma unroll
    for (int r = 0; r < 16; r++) s[r] = 0.f;
    __builtin_amdgcn_s_setprio(1);
    #pragma unroll
    for (int ds = 0; ds < 4; ds++)
      s = __builtin_amdgcn_mfma_f32_32x32x16_bf16(kf[ds], qf[ds], s, 0, 0, 0);
    __builtin_amdgcn_s_setprio(0);

    // P = exp2(S) in place; lane-local row sums (2 partials for ILP)
    #pragma unroll
    for (int r = 0; r < 16; r++) {
      s[r] = __builtin_amdgcn_exp2f(s[r]);
      if (r & 1) lsB += s[r]; else lsA += s[r];
    }

    // per-ks: pack 8 P values -> permlane -> B-frag -> 2 PV MFMAs (keeps pack regs transient)
    #pragma unroll
    for (int ks = 0; ks < 2; ks++) {
      unsigned int a0, a1, b0, b1;
      __asm__("v_cvt_pk_bf16_f32 %0, %1, %2" : "=v"(a0) : "v"(s[8 * ks + 0]), "v"(s[8 * ks + 1]));
      __asm__("v_cvt_pk_bf16_f32 %0, %1, %2" : "=v"(a1) : "v"(s[8 * ks + 2]), "v"(s[8 * ks + 3]));
      __asm__("v_cvt_pk_bf16_f32 %0, %1, %2" : "=v"(b0) : "v"(s[8 * ks + 4]), "v"(s[8 * ks + 5]));
      __asm__("v_cvt_pk_bf16_f32 %0, %1, %2" : "=v"(b1) : "v"(s[8 * ks + 6]), "v"(s[8 * ks + 7]));
      __asm__("v_permlane32_swap_b32 %0, %1" : "+v"(a0), "+v"(b0));
      __asm__("v_permlane32_swap_b32 %0, %1" : "+v"(a1), "+v"(b1));
      union { unsigned int u[4]; short8 s8; } fu;
      fu.u[0] = a0; fu.u[1] = a1; fu.u[2] = b0; fu.u[3] = b1;
      short8 pf = fu.s8;

      int slice = kvh * 2 + ks;
      __builtin_amdgcn_s_setprio(1);
      #pragma unroll
      for (int dt = 0; dt < 2; dt++) {
        short8 vf = *(const short8*)(Vs + (dt * 32 + l31) * 128 + ((32 * slice + 16 * hi) ^ fr0 ^ (dt << 6)));
        accd[dt] = __builtin_amdgcn_mfma_f32_32x32x16_bf16(vf, pf, accd[dt], 0, 0, 0);
      }
      __builtin_amdgcn_s_setprio(0);
    }

    SBAR; SCHED;                                   // all waves done reading buf b
    if (kt < S_LEN / 64 - 2) stageKV(kt + 2, b);   // overwrite buf b for tile kt+2
  }

  // ---- epilogue: combine the two kvh partials (O_num, l additive), normalize, store ----
  float lsum = lsA + lsB;
  float l2 = lsum + __shfl_xor(lsum, 32);          // full sum over own kv-half for q=l31

  // exchange via retired K/V buffers: wave region w*8KB, lane*128B, 16B-swizzled
  char* Xw = lds + w * 8192;
  const int xsw = (lane & 7) << 4;
  #pragma unroll
  for (int dt = 0; dt < 2; dt++) {
    #pragma unroll
    for (int m = 0; m < 4; m++) {
      float4 v4;
      v4.x = accd[dt][4 * m + 0]; v4.y = accd[dt][4 * m + 1];
      v4.z = accd[dt][4 * m + 2]; v4.w = accd[dt][4 * m + 3];
      *(float4*)(Xw + lane * 128 + ((dt * 64 + m * 16) ^ xsw)) = v4;
    }
  }
  if (hi == 0) Lx[w * 32 + l31] = l2;
  LG0;
  SBAR; SCHED;

  const char* Xr = lds + (w ^ 2) * 8192;           // partner: same qh, other kvh
  float inv = 1.0f / (l2 + Lx[(w ^ 2) * 32 + l31]);
  int b_ = bh >> 4, h = bh & 15;
  int q = q0 + qh * 32 + l31;
  unsigned short* Orow = O + (size_t)(b_ * S_LEN + q) * D_MODEL + h * 64;
  #pragma unroll
  for (int m = 0; m < 4; m++) {                    // store own d-half: dt = kvh
    float4 pv = *(const float4*)(Xr + lane * 128 + ((kvh * 64 + m * 16) ^ xsw));
    u16x4 ov;
    ov[0] = f2b((accd[kvh][4 * m + 0] + pv.x) * inv);
    ov[1] = f2b((accd[kvh][4 * m + 1] + pv.y) * inv);
    ov[2] = f2b((accd[kvh][4 * m + 2] + pv.z) * inv);
    ov[3] = f2b((accd[kvh][4 * m + 3] + pv.w) * inv);
    *(u16x4*)(Orow + kvh * 32 + 8 * m + 4 * hi) = ov;
  }
}

// ---------------- kernel 4: out = attn @ Wo + bo, 64x128 tile, TRIPLE-buffered, counted vmcnt ----------------
__global__ __launch_bounds__(256, 2) void k_gemm_out(
    const unsigned short* __restrict__ ab, const unsigned short* __restrict__ woT,
    const float* __restrict__ bo, float* __restrict__ out) {
  __shared__ __align__(16) char lds[36864];        // A 3x4KB at 0, B 3x8KB at 12288
  const int t = threadIdx.x, w = t >> 6, lane = t & 63;
  const int g = lane >> 4, l15 = lane & 15;
  int m0 = blockIdx.y * 64, n0 = blockIdx.x * 128;
  floatx4 acc[4][2];
  floatx4 zf = {0.f, 0.f, 0.f, 0.f};
  #pragma unroll
  for (int m = 0; m < 4; m++) { acc[m][0] = zf; acc[m][1] = zf; }

  auto stage = [&](int kt, int bi) {
    {
      int row = t >> 2, ce = (t & 3) << 3;
      gload_lds16(ab + (size_t)(m0 + row) * D_MODEL + kt * 32 + ce,
                  lds + bi * 4096 + w * 1024);
    }
    #pragma unroll
    for (int i = 0; i < 2; i++) {
      int p = i * 256 + t;
      int row = p >> 2, ce = (p & 3) << 3;
      gload_lds16(woT + (size_t)(n0 + row) * D_MODEL + kt * 32 + ce,
                  lds + 12288 + bi * 8192 + i * 4096 + w * 1024);
    }
  };

  stage(0, 0);
  stage(1, 1);
  int bi = 0;
  for (int kt = 0; kt < 32; kt++) {
    if (kt < 31) { VM3; } else { VM0; }
    SBAR; SCHED;
    if (kt < 30) {
      int b2 = bi + 2; if (b2 >= 3) b2 -= 3;
      stage(kt + 2, b2);
    }
    const char* As = lds + bi * 4096;
    const char* Bs = lds + 12288 + bi * 8192;
    short8 af[4], bfr[2];
    #pragma unroll
    for (int m = 0; m < 4; m++)
      af[m] = *(const short8*)(As + (m * 16 + l15) * 64 + g * 16);
    #pragma unroll
    for (int n = 0; n < 2; n++)
      bfr[n] = *(const short8*)(Bs + (w * 32 + n * 16 + l15) * 64 + g * 16);
    __builtin_amdgcn_s_setprio(1);
    #pragma unroll
    for (int m = 0; m < 4; m++)
      #pragma unroll
      for (int n = 0; n < 2; n++)
        acc[m][n] = __builtin_amdgcn_mfma_f32_16x16x32_bf16(af[m], bfr[n], acc[m][n], 0, 0, 0);
    __builtin_amdgcn_s_setprio(0);
    bi++; if (bi == 3) bi = 0;
  }

  #pragma unroll
  for (int m = 0; m < 4; m++) {
    #pragma unroll
    for (int n = 0; n < 2; n++) {
      #pragma unroll
      for (int j = 0; j < 4; j++) {
        int row = m0 + m * 16 + g * 4 + j;
        int col = n0 + w * 32 + n * 16 + l15;
        out[(size_t)row * D_MODEL + col] = acc[m][n][j] + bo[col];
      }
    }
  }
}

// ---------------- launch ----------------
extern "C" void kernel_launch(void* const* d_in, const int* in_sizes, int n_in,
                              void* d_out, int out_size, void* d_ws, size_t ws_size,
                              hipStream_t stream) {
  const float* x  = (const float*)d_in[0];
  const float* wq = (const float*)d_in[1];
  const float* bq = (const float*)d_in[2];
  const float* wk = (const float*)d_in[3];
  const float* bk = (const float*)d_in[4];
  const float* wv = (const float*)d_in[5];
  const float* bv = (const float*)d_in[6];
  const float* wo = (const float*)d_in[7];
  const float* bo = (const float*)d_in[8];
  float* out = (float*)d_out;

  // workspace layout (bytes), total 41.9MB
  char* ws = (char*)d_ws;
  unsigned short* xb    = (unsigned short*)(ws);              // 8.39MB x bf16 (reused: attn out)
  unsigned short* wqkvT = (unsigned short*)(ws + 8388608);    // 6.29MB [3072][1024]
  unsigned short* woT   = (unsigned short*)(ws + 14680064);   // 2.10MB [1024][1024]
  unsigned short* qb    = (unsigned short*)(ws + 16777216);   // 8.39MB [BH][S][64]
  unsigned short* kb    = (unsigned short*)(ws + 25165824);   // 8.39MB [BH][S][64]
  unsigned short* vtb   = (unsigned short*)(ws + 33554432);   // 8.39MB [BH][64][S]
  unsigned short* ab    = xb;                                 // attn output reuses xb

  k_prep<<<8192, 256, 0, stream>>>(x, wq, wk, wv, wo, xb, wqkvT, woT);
  k_gemm_qkv<<<dim3(24, 32), 256, 0, stream>>>(xb, wqkvT, bq, bk, bv, qb, kb, vtb);
  k_attn<<<1024, 256, 0, stream>>>(qb, kb, vtb, ab);
  k_gemm_out<<<dim3(8, 64), 256, 0, stream>>>(ab, woT, bo, out);
}

// Round 11
// 192.020 us; speedup vs baseline: 1.0325x; 1.0325x over previous
//
#include <hip/hip_runtime.h>
#include <cstdint>
#include <cstddef>

// ---- problem constants ----
#define D_MODEL 1024
#define S_LEN   2048
#define NHEAD   16
#define DHEAD   64
#define BSZ     2
#define LOG2E   1.44269504088896f

typedef short  short8   __attribute__((ext_vector_type(8)));
typedef float  floatx4  __attribute__((ext_vector_type(4)));
typedef float  floatx16 __attribute__((ext_vector_type(16)));
typedef unsigned short u16x4 __attribute__((ext_vector_type(4)));

#define VM4  __asm__ volatile("s_waitcnt vmcnt(4)" ::: "memory")
#define VM3  __asm__ volatile("s_waitcnt vmcnt(3)" ::: "memory")
#define VM0  __asm__ volatile("s_waitcnt vmcnt(0)" ::: "memory")
#define LG0  __asm__ volatile("s_waitcnt lgkmcnt(0)" ::: "memory")
#define SBAR __builtin_amdgcn_s_barrier()
#define SCHED __builtin_amdgcn_sched_barrier(0)

__device__ inline unsigned short f2b(float f) {
  union { float f; unsigned int u; } v; v.f = f;
  unsigned int r = v.u + 0x7FFFu + ((v.u >> 16) & 1u);   // RNE
  return (unsigned short)(r >> 16);
}

// async global->LDS, 16B per lane. LDS dest must be wave-uniform base (+lane*16 implicit).
__device__ inline void gload_lds16(const void* g, void* l) {
  __builtin_amdgcn_global_load_lds(
      (const __attribute__((address_space(1))) unsigned int*)g,
      (__attribute__((address_space(3))) unsigned int*)l, 16, 0, 0);
}

// ---------------- kernel 1: fused prep (x->bf16 convert + 4 weight transpose-converts) ----------------
__global__ __launch_bounds__(256) void k_prep(
    const float* __restrict__ x,
    const float* __restrict__ wq, const float* __restrict__ wk,
    const float* __restrict__ wv, const float* __restrict__ wo,
    unsigned short* __restrict__ xb, unsigned short* __restrict__ wqkvT,
    unsigned short* __restrict__ woT) {
  int bid = blockIdx.x;
  if (bid < 4096) {
    int i = bid * 256 + threadIdx.x;
    float4 f = ((const float4*)x)[i];
    u16x4 o;
    o[0] = f2b(f.x); o[1] = f2b(f.y); o[2] = f2b(f.z); o[3] = f2b(f.w);
    ((u16x4*)xb)[i] = o;
    return;
  }
  __shared__ float tile[32][33];
  int r = bid - 4096;
  int which = r >> 10, tl = r & 1023;
  const float* src = (which == 0) ? wq : (which == 1) ? wk : (which == 2) ? wv : wo;
  unsigned short* dst = (which < 3) ? (wqkvT + (size_t)which * 1024 * 1024) : woT;
  int bx = (tl & 31) * 32;   // n block
  int by = (tl >> 5) * 32;   // k block
  int tx = threadIdx.x & 31, ty0 = threadIdx.x >> 5;
  #pragma unroll
  for (int i = 0; i < 4; i++) {
    int ty = ty0 + i * 8;
    tile[ty][tx] = src[(size_t)(by + ty) * D_MODEL + bx + tx];
  }
  __syncthreads();
  #pragma unroll
  for (int i = 0; i < 4; i++) {
    int ty = ty0 + i * 8;
    dst[(size_t)(bx + ty) * D_MODEL + by + tx] = f2b(tile[tx][ty]);
  }
}

// ---------------- shared GEMM mainloop: 128x128 tile, BK=32, TRIPLE-buffered, counted vmcnt ----------------
__device__ inline void gemm_tiles(const unsigned short* __restrict__ A,
                                  const unsigned short* __restrict__ Bt,
                                  int m0, int n0, char* lds, floatx4 acc[4][4]) {
  const int t = threadIdx.x, w = t >> 6, lane = t & 63;
  const int wr = w >> 1, wc = w & 1, g = lane >> 4, l15 = lane & 15;
  floatx4 zf = {0.f, 0.f, 0.f, 0.f};
  #pragma unroll
  for (int m = 0; m < 4; m++)
    #pragma unroll
    for (int n = 0; n < 4; n++) acc[m][n] = zf;

  auto stage = [&](int kt, int bi) {
    #pragma unroll
    for (int i = 0; i < 2; i++) {
      int p = i * 256 + t;
      int row = p >> 2, ce = (p & 3) << 3;
      gload_lds16(A  + (size_t)(m0 + row) * D_MODEL + kt * 32 + ce,
                  lds + bi * 8192 + i * 4096 + w * 1024);
      gload_lds16(Bt + (size_t)(n0 + row) * D_MODEL + kt * 32 + ce,
                  lds + 24576 + bi * 8192 + i * 4096 + w * 1024);
    }
  };

  stage(0, 0);
  stage(1, 1);
  int bi = 0;
  for (int kt = 0; kt < 32; kt++) {
    if (kt < 31) { VM4; } else { VM0; }
    SBAR; SCHED;
    if (kt < 30) {
      int b2 = bi + 2; if (b2 >= 3) b2 -= 3;
      stage(kt + 2, b2);
    }
    const char* As = lds + bi * 8192;
    const char* Bs = lds + 24576 + bi * 8192;
    short8 af[4], bfr[4];
    #pragma unroll
    for (int m = 0; m < 4; m++)
      af[m] = *(const short8*)(As + (wr * 64 + m * 16 + l15) * 64 + g * 16);
    #pragma unroll
    for (int n = 0; n < 4; n++)
      bfr[n] = *(const short8*)(Bs + (wc * 64 + n * 16 + l15) * 64 + g * 16);
    __builtin_amdgcn_s_setprio(1);
    #pragma unroll
    for (int m = 0; m < 4; m++)
      #pragma unroll
      for (int n = 0; n < 4; n++)
        acc[m][n] = __builtin_amdgcn_mfma_f32_16x16x32_bf16(af[m], bfr[n], acc[m][n], 0, 0, 0);
    __builtin_amdgcn_s_setprio(0);
    bi++; if (bi == 3) bi = 0;
  }
}

// ---------------- kernel 2: QKV GEMM, epilogue scatters Q/K per-head and V TRANSPOSED ----------------
__global__ __launch_bounds__(256, 3) void k_gemm_qkv(
    const unsigned short* __restrict__ xb, const unsigned short* __restrict__ wT,
    const float* __restrict__ bq, const float* __restrict__ bk, const float* __restrict__ bv,
    unsigned short* __restrict__ qb, unsigned short* __restrict__ kb,
    unsigned short* __restrict__ vtb) {
  __shared__ __align__(16) char lds[49152];
  floatx4 acc[4][4];
  int m0 = blockIdx.y * 128, n0 = blockIdx.x * 128;
  gemm_tiles(xb, wT, m0, n0, lds, acc);
  int t = threadIdx.x, w = t >> 6, lane = t & 63;
  int wr = w >> 1, wc = w & 1, g = lane >> 4, l15 = lane & 15;
  #pragma unroll
  for (int m = 0; m < 4; m++) {
    #pragma unroll
    for (int n = 0; n < 4; n++) {
      int row0 = m0 + wr * 64 + m * 16 + g * 4;          // token base (4 j's contiguous)
      int col  = n0 + wc * 64 + n * 16 + l15;            // 0..3071
      int sel = col >> 10, c = col & 1023;
      int h = c >> 6, dd = c & 63;
      int b_ = row0 >> 11, ss = row0 & 2047;
      if (sel == 2) {
        u16x4 o;
        #pragma unroll
        for (int j = 0; j < 4; j++) o[j] = f2b(acc[m][n][j] + bv[c]);
        *(u16x4*)(vtb + ((size_t)(b_ * NHEAD + h) * DHEAD + dd) * S_LEN + ss) = o;
      } else {
        const float* bias = (sel == 0) ? bq : bk;
        unsigned short* dst = (sel == 0) ? qb : kb;
        float sc = (sel == 0) ? 0.125f * LOG2E : 1.0f;
        #pragma unroll
        for (int j = 0; j < 4; j++) {
          float v = (acc[m][n][j] + bias[c]) * sc;
          dst[(size_t)((b_ * NHEAD + h) * S_LEN + ss + j) * DHEAD + dd] = f2b(v);
        }
      }
    }
  }
}

// ---------------- kernel 3: flash attention, 4 waves = (qh, kvh) quadrants ----------------
// Round-9 structure with the REAL spill cause fixed: epilogue indexed accd[kvh] with a
// runtime index -> whole accumulator demoted to scratch (rule #20: localMem; explains
// VGPR_Count=64 + 5MB extra WRITE in rounds 8-9). Now a wave-uniform static vector
// select keeps accd in registers end-to-end.
__global__ __launch_bounds__(256)
__attribute__((amdgpu_waves_per_eu(4, 4)))
void k_attn(
    const unsigned short* __restrict__ Q, const unsigned short* __restrict__ K,
    const unsigned short* __restrict__ Vt, unsigned short* __restrict__ O) {
  __shared__ __align__(16) char lds[33280];
  char* KsB0 = lds;              // 8KB K buf0
  char* KsB1 = lds + 8192;
  char* VsB0 = lds + 16384;      // 8KB V buf0
  char* VsB1 = lds + 24576;      // 8KB V buf1 (holds Q during prologue)
  float* Lx  = (float*)(lds + 32768);   // 128 floats: per-wave l exchange

  // XCD swizzle: bh -> XCD (bh&7); per-XCD KV working set = 4 bh * 512KB = 2MB (fits L2)
  int L = blockIdx.x;
  int bh = (L & 7) + 8 * (L >> 8);
  int qt = (L >> 3) & 31;

  int t = threadIdx.x, w = t >> 6, lane = t & 63, l31 = lane & 31, hi = lane >> 5;
  int qh = w & 1, kvh = w >> 1;
  const unsigned short* Qh = Q + (size_t)bh * S_LEN * DHEAD;
  const unsigned short* Kh = K + (size_t)bh * S_LEN * DHEAD;
  const unsigned short* Vh = Vt + (size_t)bh * DHEAD * S_LEN;
  int q0 = qt * 64;

  auto stageKV = [&](int kt, int b) {
    char* Kd = b ? KsB1 : KsB0;
    char* Vd = b ? VsB1 : VsB0;
    #pragma unroll
    for (int i = 0; i < 2; i++) {
      int p = i * 256 + t;
      int row = p >> 3;
      int sb = ((p & 7) ^ ((row ^ (row >> 3)) & 7)) << 4;
      gload_lds16(Kh + (size_t)(kt * 64 + row) * DHEAD + (sb >> 1), Kd + i * 4096 + w * 1024);
      gload_lds16(Vh + (size_t)row * S_LEN + kt * 64 + (sb >> 1),   Vd + i * 4096 + w * 1024);
    }
  };

  // prologue: stage Q (into VsB1) + KV tile 0 (buf0); one-time full drain
  #pragma unroll
  for (int i = 0; i < 2; i++) {
    int p = i * 256 + t;
    int row = p >> 3;
    int sb = ((p & 7) ^ ((row ^ (row >> 3)) & 7)) << 4;
    gload_lds16(Qh + (size_t)(q0 + row) * DHEAD + (sb >> 1), VsB1 + i * 4096 + w * 1024);
  }
  stageKV(0, 0);
  __syncthreads();                       // Q + tile0 landed (full drain, once)

  const int fr0 = ((l31 ^ (l31 >> 3)) & 7) << 4;
  short8 qf[4];
  #pragma unroll
  for (int ds = 0; ds < 4; ds++)
    qf[ds] = *(const short8*)(VsB1 + (qh * 32 + l31) * 128 + ((32 * ds + 16 * hi) ^ fr0 ^ (qh << 6)));
  LG0;                                   // Q in regs
  SBAR; SCHED;                           // all waves done reading VsB1
  stageKV(1, 1);                         // 4 loads in flight

  floatx16 accd[2];
  #pragma unroll
  for (int dt = 0; dt < 2; dt++)
    #pragma unroll
    for (int r = 0; r < 16; r++) accd[dt][r] = 0.f;
  float lsA = 0.f, lsB = 0.f;

  #pragma unroll 2
  for (int kt = 0; kt < S_LEN / 64; kt++) {
    int b = kt & 1;
    char* Ks = b ? KsB1 : KsB0;
    char* Vs = b ? VsB1 : VsB0;
    if (kt < S_LEN / 64 - 1) { VM4; } else { VM0; }   // tile kt landed; kt+1 in flight
    SBAR; SCHED;                                       // tile kt visible to all waves

    // S^T[kv32][q32] = K * Q^T for own quadrant: A rows kv = kvh*32 + l31
    short8 kf[4];
    #pragma unroll
    for (int ds = 0; ds < 4; ds++)
      kf[ds] = *(const short8*)(Ks + (kvh * 32 + l31) * 128 + ((32 * ds + 16 * hi) ^ fr0 ^ (kvh << 6)));
    floatx16 s;
    #pragma unroll
    for (int r = 0; r < 16; r++) s[r] = 0.f;
    __builtin_amdgcn_s_setprio(1);
    #pragma unroll
    for (int ds = 0; ds < 4; ds++)
      s = __builtin_amdgcn_mfma_f32_32x32x16_bf16(kf[ds], qf[ds], s, 0, 0, 0);
    __builtin_amdgcn_s_setprio(0);

    // P = exp2(S) in place; lane-local row sums (2 partials for ILP)
    #pragma unroll
    for (int r = 0; r < 16; r++) {
      s[r] = __builtin_amdgcn_exp2f(s[r]);
      if (r & 1) lsB += s[r]; else lsA += s[r];
    }

    // per-ks: pack 8 P values -> permlane -> B-frag -> 2 PV MFMAs (keeps pack regs transient)
    #pragma unroll
    for (int ks = 0; ks < 2; ks++) {
      unsigned int a0, a1, b0, b1;
      __asm__("v_cvt_pk_bf16_f32 %0, %1, %2" : "=v"(a0) : "v"(s[8 * ks + 0]), "v"(s[8 * ks + 1]));
      __asm__("v_cvt_pk_bf16_f32 %0, %1, %2" : "=v"(a1) : "v"(s[8 * ks + 2]), "v"(s[8 * ks + 3]));
      __asm__("v_cvt_pk_bf16_f32 %0, %1, %2" : "=v"(b0) : "v"(s[8 * ks + 4]), "v"(s[8 * ks + 5]));
      __asm__("v_cvt_pk_bf16_f32 %0, %1, %2" : "=v"(b1) : "v"(s[8 * ks + 6]), "v"(s[8 * ks + 7]));
      __asm__("v_permlane32_swap_b32 %0, %1" : "+v"(a0), "+v"(b0));
      __asm__("v_permlane32_swap_b32 %0, %1" : "+v"(a1), "+v"(b1));
      union { unsigned int u[4]; short8 s8; } fu;
      fu.u[0] = a0; fu.u[1] = a1; fu.u[2] = b0; fu.u[3] = b1;
      short8 pf = fu.s8;

      int slice = kvh * 2 + ks;
      __builtin_amdgcn_s_setprio(1);
      #pragma unroll
      for (int dt = 0; dt < 2; dt++) {
        short8 vf = *(const short8*)(Vs + (dt * 32 + l31) * 128 + ((32 * slice + 16 * hi) ^ fr0 ^ (dt << 6)));
        accd[dt] = __builtin_amdgcn_mfma_f32_32x32x16_bf16(vf, pf, accd[dt], 0, 0, 0);
      }
      __builtin_amdgcn_s_setprio(0);
    }

    SBAR; SCHED;                                   // all waves done reading buf b
    if (kt < S_LEN / 64 - 2) stageKV(kt + 2, b);   // overwrite buf b for tile kt+2
  }

  // ---- epilogue: combine the two kvh partials (O_num, l additive), normalize, store ----
  float lsum = lsA + lsB;
  float l2 = lsum + __shfl_xor(lsum, 32);          // full sum over own kv-half for q=l31

  // exchange via retired K/V buffers: wave region w*8KB, lane*128B, 16B-swizzled
  char* Xw = lds + w * 8192;
  const int xsw = (lane & 7) << 4;
  #pragma unroll
  for (int dt = 0; dt < 2; dt++) {
    #pragma unroll
    for (int m = 0; m < 4; m++) {
      float4 v4;
      v4.x = accd[dt][4 * m + 0]; v4.y = accd[dt][4 * m + 1];
      v4.z = accd[dt][4 * m + 2]; v4.w = accd[dt][4 * m + 3];
      *(float4*)(Xw + lane * 128 + ((dt * 64 + m * 16) ^ xsw)) = v4;
    }
  }
  if (hi == 0) Lx[w * 32 + l31] = l2;
  LG0;
  SBAR; SCHED;

  // own d-half with STATIC register indexing (rule #20: accd[kvh] would demote to scratch)
  floatx16 ownAcc;
  if (kvh == 0) ownAcc = accd[0]; else ownAcc = accd[1];

  const char* Xr = lds + (w ^ 2) * 8192;           // partner: same qh, other kvh
  float inv = 1.0f / (l2 + Lx[(w ^ 2) * 32 + l31]);
  int b_ = bh >> 4, h = bh & 15;
  int q = q0 + qh * 32 + l31;
  unsigned short* Orow = O + (size_t)(b_ * S_LEN + q) * D_MODEL + h * 64;
  #pragma unroll
  for (int m = 0; m < 4; m++) {                    // store own d-half: dt = kvh
    float4 pv = *(const float4*)(Xr + lane * 128 + ((kvh * 64 + m * 16) ^ xsw));
    u16x4 ov;
    ov[0] = f2b((ownAcc[4 * m + 0] + pv.x) * inv);
    ov[1] = f2b((ownAcc[4 * m + 1] + pv.y) * inv);
    ov[2] = f2b((ownAcc[4 * m + 2] + pv.z) * inv);
    ov[3] = f2b((ownAcc[4 * m + 3] + pv.w) * inv);
    *(u16x4*)(Orow + kvh * 32 + 8 * m + 4 * hi) = ov;
  }
}

// ---------------- kernel 4: out = attn @ Wo + bo, 64x128 tile, TRIPLE-buffered, counted vmcnt ----------------
__global__ __launch_bounds__(256, 2) void k_gemm_out(
    const unsigned short* __restrict__ ab, const unsigned short* __restrict__ woT,
    const float* __restrict__ bo, float* __restrict__ out) {
  __shared__ __align__(16) char lds[36864];        // A 3x4KB at 0, B 3x8KB at 12288
  const int t = threadIdx.x, w = t >> 6, lane = t & 63;
  const int g = lane >> 4, l15 = lane & 15;
  int m0 = blockIdx.y * 64, n0 = blockIdx.x * 128;
  floatx4 acc[4][2];
  floatx4 zf = {0.f, 0.f, 0.f, 0.f};
  #pragma unroll
  for (int m = 0; m < 4; m++) { acc[m][0] = zf; acc[m][1] = zf; }

  auto stage = [&](int kt, int bi) {
    {
      int row = t >> 2, ce = (t & 3) << 3;
      gload_lds16(ab + (size_t)(m0 + row) * D_MODEL + kt * 32 + ce,
                  lds + bi * 4096 + w * 1024);
    }
    #pragma unroll
    for (int i = 0; i < 2; i++) {
      int p = i * 256 + t;
      int row = p >> 2, ce = (p & 3) << 3;
      gload_lds16(woT + (size_t)(n0 + row) * D_MODEL + kt * 32 + ce,
                  lds + 12288 + bi * 8192 + i * 4096 + w * 1024);
    }
  };

  stage(0, 0);
  stage(1, 1);
  int bi = 0;
  for (int kt = 0; kt < 32; kt++) {
    if (kt < 31) { VM3; } else { VM0; }
    SBAR; SCHED;
    if (kt < 30) {
      int b2 = bi + 2; if (b2 >= 3) b2 -= 3;
      stage(kt + 2, b2);
    }
    const char* As = lds + bi * 4096;
    const char* Bs = lds + 12288 + bi * 8192;
    short8 af[4], bfr[2];
    #pragma unroll
    for (int m = 0; m < 4; m++)
      af[m] = *(const short8*)(As + (m * 16 + l15) * 64 + g * 16);
    #pragma unroll
    for (int n = 0; n < 2; n++)
      bfr[n] = *(const short8*)(Bs + (w * 32 + n * 16 + l15) * 64 + g * 16);
    __builtin_amdgcn_s_setprio(1);
    #pragma unroll
    for (int m = 0; m < 4; m++)
      #pragma unroll
      for (int n = 0; n < 2; n++)
        acc[m][n] = __builtin_amdgcn_mfma_f32_16x16x32_bf16(af[m], bfr[n], acc[m][n], 0, 0, 0);
    __builtin_amdgcn_s_setprio(0);
    bi++; if (bi == 3) bi = 0;
  }

  #pragma unroll
  for (int m = 0; m < 4; m++) {
    #pragma unroll
    for (int n = 0; n < 2; n++) {
      #pragma unroll
      for (int j = 0; j < 4; j++) {
        int row = m0 + m * 16 + g * 4 + j;
        int col = n0 + w * 32 + n * 16 + l15;
        out[(size_t)row * D_MODEL + col] = acc[m][n][j] + bo[col];
      }
    }
  }
}

// ---------------- launch ----------------
extern "C" void kernel_launch(void* const* d_in, const int* in_sizes, int n_in,
                              void* d_out, int out_size, void* d_ws, size_t ws_size,
                              hipStream_t stream) {
  const float* x  = (const float*)d_in[0];
  const float* wq = (const float*)d_in[1];
  const float* bq = (const float*)d_in[2];
  const float* wk = (const float*)d_in[3];
  const float* bk = (const float*)d_in[4];
  const float* wv = (const float*)d_in[5];
  const float* bv = (const float*)d_in[6];
  const float* wo = (const float*)d_in[7];
  const float* bo = (const float*)d_in[8];
  float* out = (float*)d_out;

  // workspace layout (bytes), total 41.9MB
  char* ws = (char*)d_ws;
  unsigned short* xb    = (unsigned short*)(ws);              // 8.39MB x bf16 (reused: attn out)
  unsigned short* wqkvT = (unsigned short*)(ws + 8388608);    // 6.29MB [3072][1024]
  unsigned short* woT   = (unsigned short*)(ws + 14680064);   // 2.10MB [1024][1024]
  unsigned short* qb    = (unsigned short*)(ws + 16777216);   // 8.39MB [BH][S][64]
  unsigned short* kb    = (unsigned short*)(ws + 25165824);   // 8.39MB [BH][S][64]
  unsigned short* vtb   = (unsigned short*)(ws + 33554432);   // 8.39MB [BH][64][S]
  unsigned short* ab    = xb;                                 // attn output reuses xb

  k_prep<<<8192, 256, 0, stream>>>(x, wq, wk, wv, wo, xb, wqkvT, woT);
  k_gemm_qkv<<<dim3(24, 32), 256, 0, stream>>>(xb, wqkvT, bq, bk, bv, qb, kb, vtb);
  k_attn<<<1024, 256, 0, stream>>>(qb, kb, vtb, ab);
  k_gemm_out<<<dim3(8, 64), 256, 0, stream>>>(ab, woT, bo, out);
}